// Round 13
// baseline (563.943 us; speedup 1.0000x reference)
//
#include <hip/hip_runtime.h>
#include <hip/hip_bf16.h>
#include <stdint.h>

#define KD 256
#define NPIX 131072
#define NCM 190
#define CMP 192
#define LAMBDA 0.00390625f
#define LN_EPS 1e-5f
#define TM 16          // pixel rows per tile
#define NTILES 8192    // NPIX / TM
#define GRID_MAIN 768  // 256 CU x 3 blocks (LDS-bound)

typedef __attribute__((ext_vector_type(4))) float f32x4;
typedef __attribute__((ext_vector_type(8))) short bf16x8;

__device__ __forceinline__ float wred64(float v) {
#pragma unroll
  for (int off = 32; off > 0; off >>= 1) v += __shfl_xor(v, off, 64);
  return v;
}

__device__ __forceinline__ float wred16(float v) {
#pragma unroll
  for (int off = 8; off > 0; off >>= 1) v += __shfl_xor(v, off, 64);
  return v;
}

// round-to-nearest-even f32 -> bf16 bits
__device__ __forceinline__ ushort f2bf(float f) {
  uint32_t u = __float_as_uint(f);
  u += 0x7FFFu + ((u >> 16) & 1u);
  return (ushort)(u >> 16);
}

// async HBM->LDS 16B/lane; src per-lane, dst wave-uniform base (R10-verified)
__device__ __forceinline__ void gload_lds16(const float* g, float* l) {
  __builtin_amdgcn_global_load_lds(
      (const __attribute__((address_space(1))) unsigned int*)(const void*)g,
      (__attribute__((address_space(3))) unsigned int*)(void*)l, 16, 0, 0);
}

// ---------------- kernel 1: prototype-side prep (tiny) ----------------
__global__ __launch_bounds__(256) void proto_prep_kernel(
    const float* __restrict__ protos, const float* __restrict__ pvar,
    const float* __restrict__ gam, const float* __restrict__ bet,
    const float* __restrict__ eps_p,
    ushort* __restrict__ Bp, float* __restrict__ spc) {
  const int wave = threadIdx.x >> 6;
  const int lane = threadIdx.x & 63;
  const int cm = blockIdx.x * 4 + wave;
  if (cm >= CMP) return;
  ushort* row = Bp + (size_t)cm * 512;
  if (cm >= NCM) {  // zero pad rows 190,191
    for (int j = lane; j < 512; j += 64) row[j] = 0;
    if (lane == 0) spc[cm] = 0.f;
    return;
  }
  const int k0 = lane * 4;
  f32x4 pv = *(const f32x4*)(pvar + (size_t)cm * KD + k0);
  f32x4 pm = *(const f32x4*)(protos + (size_t)cm * KD + k0);
  f32x4 gg = *(const f32x4*)(gam + k0);
  f32x4 bb = *(const f32x4*)(bet + k0);
  float spv = wred64(pv.x + pv.y + pv.z + pv.w);
  f32x4 acc = {0.f, 0.f, 0.f, 0.f};
#pragma unroll
  for (int r = 0; r < 2; ++r) {
    f32x4 e = *(const f32x4*)(eps_p + ((size_t)r * NCM + cm) * KD + k0);
    f32x4 v;
    v.x = e.x * pv.x + pm.x;
    v.y = e.y * pv.y + pm.y;
    v.z = e.z * pv.z + pm.z;
    v.w = e.w * pv.w + pm.w;
    float s1 = wred64(v.x + v.y + v.z + v.w);
    float s2 = wred64(v.x * v.x + v.y * v.y + v.z * v.z + v.w * v.w);
    float mean = s1 * (1.f / KD);
    float var = s2 * (1.f / KD) - mean * mean;
    float rs = rsqrtf(var + LN_EPS);
    f32x4 y;
    y.x = (v.x - mean) * rs * gg.x + bb.x;
    y.y = (v.y - mean) * rs * gg.y + bb.y;
    y.z = (v.z - mean) * rs * gg.z + bb.z;
    y.w = (v.w - mean) * rs * gg.w + bb.w;
    float n2 = wred64(y.x * y.x + y.y * y.y + y.z * y.z + y.w * y.w);
    float inv = 1.f / fmaxf(sqrtf(n2), 1e-12f);
    acc.x += y.x * inv;
    acc.y += y.y * inv;
    acc.z += y.z * inv;
    acc.w += y.w * inv;
  }
  row[k0 + 0] = f2bf(acc.x);
  row[k0 + 1] = f2bf(acc.y);
  row[k0 + 2] = f2bf(acc.z);
  row[k0 + 3] = f2bf(acc.w);
  const float s = 2.f * LAMBDA;
  row[256 + k0 + 0] = f2bf(s * sqrtf(pv.x));
  row[256 + k0 + 1] = f2bf(s * sqrtf(pv.y));
  row[256 + k0 + 2] = f2bf(s * sqrtf(pv.z));
  row[256 + k0 + 3] = f2bf(s * sqrtf(pv.w));
  if (lane == 0) spc[cm] = 2.f + LAMBDA * spv;
}

// ---------------- kernel 2: per-wave pipelined fused kernel ----------------
// 1-wave blocks, persistent grid 768 (3 blocks/CU, LDS 48KB). Per 16-row tile:
// 4 groups of 4 rows; group g+1's 16KB prefetched via global_load_lds (NO VGPR
// cost) into stage[buf^1] while group g computes from stage[buf]. Manual
// s_waitcnt vmcnt(16) drains only the older group -> wave keeps 16-32KB in
// flight through phase A. 3 waves/CU x ~16KB pending > 22KB/CU Little's-law
// target for 6.3 TB/s. Phase-A math byte-identical to validated R6 chain.
__global__ __launch_bounds__(64) void fused_main_kernel(
    const float* __restrict__ x, const float* __restrict__ xvar,
    const float* __restrict__ gam, const float* __restrict__ bet,
    const float* __restrict__ eps_x,
    const ushort* __restrict__ Bp, const float* __restrict__ spc,
    float* __restrict__ out) {
  __shared__ float stage_sh[2 * 4 * 4 * 256];  // 32 KB: [buf][arr][row][256]
  __shared__ ushort As[TM * 512];              // 16 KB packed A-tile
  __shared__ float sxl[TM];
  const int lane = threadIdx.x;  // block == one wave
  const int sub = lane >> 4;     // row within group of 4
  const int l = lane & 15;       // 16 lanes per row
  const float* e1base = eps_x + (int64_t)NPIX * KD;

  // hoisted invariants (per-lane): gamma/beta fragments
  f32x4 gg[4], bb[4];
#pragma unroll
  for (int j = 0; j < 4; ++j) {
    gg[j] = *(const f32x4*)(gam + l * 16 + 4 * j);
    bb[j] = *(const f32x4*)(bet + l * 16 + 4 * j);
  }

  // issue one group's 16 x 1KB loads (4 rows x 4 arrays) into stage[buf]
  auto issue_group = [&](int64_t n0, int buf) {
#pragma unroll
    for (int rr = 0; rr < 4; ++rr) {
      const int64_t roff = (n0 + rr) * KD + lane * 4;
      float* db = stage_sh + (buf * 16 + rr) * 256;
      gload_lds16(x + roff, db);                 // arr 0
      gload_lds16(xvar + roff, db + 4 * 256);    // arr 1
      gload_lds16(eps_x + roff, db + 8 * 256);   // arr 2
      gload_lds16(e1base + roff, db + 12 * 256); // arr 3
    }
  };

  for (int tile = blockIdx.x; tile < NTILES; tile += GRID_MAIN) {
    const int64_t nbase = (int64_t)tile * TM;
    issue_group(nbase, 0);  // prologue

#pragma unroll
    for (int g = 0; g < 4; ++g) {
      const int buf = g & 1;
      if (g < 3) {
        issue_group(nbase + (g + 1) * 4, buf ^ 1);
        asm volatile("s_waitcnt vmcnt(16)" ::: "memory");  // drain group g only
      } else {
        asm volatile("s_waitcnt vmcnt(0)" ::: "memory");
      }
      __builtin_amdgcn_sched_barrier(0);

      // ---- compute group g from stage[buf] (math identical to R6) ----
      const int m = g * 4 + sub;
      const float* sxp = stage_sh + (buf * 16 + sub) * 256 + l * 16;
      const float* svp = sxp + 4 * 256;
      const float* se0 = sxp + 8 * 256;
      const float* se1 = sxp + 12 * 256;
      f32x4 xm[4], xv[4];
#pragma unroll
      for (int j = 0; j < 4; ++j) {
        xm[j] = *(const f32x4*)(sxp + 4 * j);
        xv[j] = *(const f32x4*)(svp + 4 * j);
      }
      float sxv = 0.f;
#pragma unroll
      for (int j = 0; j < 4; ++j) sxv += xv[j].x + xv[j].y + xv[j].z + xv[j].w;
      sxv = wred16(sxv);

      f32x4 acc[4];
#pragma unroll
      for (int j = 0; j < 4; ++j) acc[j] = (f32x4){0.f, 0.f, 0.f, 0.f};

#pragma unroll
      for (int r = 0; r < 2; ++r) {
        const float* pe = (r == 0) ? se0 : se1;
        f32x4 v[4];
        float s1 = 0.f, s2 = 0.f;
#pragma unroll
        for (int j = 0; j < 4; ++j) {
          f32x4 e = *(const f32x4*)(pe + 4 * j);
          v[j].x = e.x * xv[j].x + xm[j].x;
          v[j].y = e.y * xv[j].y + xm[j].y;
          v[j].z = e.z * xv[j].z + xm[j].z;
          v[j].w = e.w * xv[j].w + xm[j].w;
          s1 += v[j].x + v[j].y + v[j].z + v[j].w;
          s2 += v[j].x * v[j].x + v[j].y * v[j].y + v[j].z * v[j].z + v[j].w * v[j].w;
        }
        s1 = wred16(s1);
        s2 = wred16(s2);
        float mean = s1 * (1.f / KD);
        float var = s2 * (1.f / KD) - mean * mean;
        float rs = rsqrtf(var + LN_EPS);
        float n2 = 0.f;
        f32x4 y[4];
#pragma unroll
        for (int j = 0; j < 4; ++j) {
          y[j].x = (v[j].x - mean) * rs * gg[j].x + bb[j].x;
          y[j].y = (v[j].y - mean) * rs * gg[j].y + bb[j].y;
          y[j].z = (v[j].z - mean) * rs * gg[j].z + bb[j].z;
          y[j].w = (v[j].w - mean) * rs * gg[j].w + bb[j].w;
          n2 += y[j].x * y[j].x + y[j].y * y[j].y + y[j].z * y[j].z + y[j].w * y[j].w;
        }
        n2 = wred16(n2);
        float inv = 1.f / fmaxf(sqrtf(n2), 1e-12f);
#pragma unroll
        for (int j = 0; j < 4; ++j) {
          acc[j].x += y[j].x * inv;
          acc[j].y += y[j].y * inv;
          acc[j].z += y[j].z * inv;
          acc[j].w += y[j].w * inv;
        }
      }

      // pack to bf16, swizzled As row m (R1/R6 layout)
      char* rowp = (char*)As + m * 1024;
      const int sw = (m & 7) << 4;
      union {
        uint4 q;
        ushort s[8];
      } pk;
      pk.s[0] = f2bf(0.5f * acc[0].x);
      pk.s[1] = f2bf(0.5f * acc[0].y);
      pk.s[2] = f2bf(0.5f * acc[0].z);
      pk.s[3] = f2bf(0.5f * acc[0].w);
      pk.s[4] = f2bf(0.5f * acc[1].x);
      pk.s[5] = f2bf(0.5f * acc[1].y);
      pk.s[6] = f2bf(0.5f * acc[1].z);
      pk.s[7] = f2bf(0.5f * acc[1].w);
      *(uint4*)(rowp + ((l * 32) ^ sw)) = pk.q;
      pk.s[0] = f2bf(0.5f * acc[2].x);
      pk.s[1] = f2bf(0.5f * acc[2].y);
      pk.s[2] = f2bf(0.5f * acc[2].z);
      pk.s[3] = f2bf(0.5f * acc[2].w);
      pk.s[4] = f2bf(0.5f * acc[3].x);
      pk.s[5] = f2bf(0.5f * acc[3].y);
      pk.s[6] = f2bf(0.5f * acc[3].z);
      pk.s[7] = f2bf(0.5f * acc[3].w);
      *(uint4*)(rowp + ((l * 32 + 16) ^ sw)) = pk.q;
      pk.s[0] = f2bf(sqrtf(xv[0].x));
      pk.s[1] = f2bf(sqrtf(xv[0].y));
      pk.s[2] = f2bf(sqrtf(xv[0].z));
      pk.s[3] = f2bf(sqrtf(xv[0].w));
      pk.s[4] = f2bf(sqrtf(xv[1].x));
      pk.s[5] = f2bf(sqrtf(xv[1].y));
      pk.s[6] = f2bf(sqrtf(xv[1].z));
      pk.s[7] = f2bf(sqrtf(xv[1].w));
      *(uint4*)(rowp + ((512 + l * 32) ^ sw)) = pk.q;
      pk.s[0] = f2bf(sqrtf(xv[2].x));
      pk.s[1] = f2bf(sqrtf(xv[2].y));
      pk.s[2] = f2bf(sqrtf(xv[2].z));
      pk.s[3] = f2bf(sqrtf(xv[2].w));
      pk.s[4] = f2bf(sqrtf(xv[3].x));
      pk.s[5] = f2bf(sqrtf(xv[3].y));
      pk.s[6] = f2bf(sqrtf(xv[3].z));
      pk.s[7] = f2bf(sqrtf(xv[3].w));
      *(uint4*)(rowp + ((512 + l * 32 + 16) ^ sw)) = pk.q;
      if (l == 0) sxl[m] = LAMBDA * sxv;
    }

    // ---------------- Phase B: 4 col-passes, staged epilogue ----------------
    const int colq = lane & 15;
    const int kq = lane >> 4;
    const char* arow = (const char*)As + colq * 1024;
    const int swm = (colq & 7) << 4;
    float* st = stage_sh;  // stage fully consumed; reuse 12.2KB as out-stage

    for (int p = 0; p < 4; ++p) {
      f32x4 o[3];
#pragma unroll
      for (int t = 0; t < 3; ++t) o[t] = (f32x4){0.f, 0.f, 0.f, 0.f};
      const int colbase = p * 48;
#pragma unroll
      for (int kk = 0; kk < 16; ++kk) {
        const int kbyte = kk * 64 + kq * 16;
        bf16x8 af = *(const bf16x8*)(arow + (kbyte ^ swm));
#pragma unroll
        for (int t = 0; t < 3; ++t) {
          const int cmc = colbase + t * 16 + colq;
          bf16x8 bfr = *(const bf16x8*)((const char*)Bp + (size_t)cmc * 1024 + kbyte);
          o[t] = __builtin_amdgcn_mfma_f32_16x16x32_bf16(af, bfr, o[t], 0, 0, 0);
        }
      }
#pragma unroll
      for (int t = 0; t < 3; ++t) {
        const int col = colbase + t * 16 + colq;
        if (col < NCM) {
          const float sc = spc[col];
#pragma unroll
          for (int j = 0; j < 4; ++j) {
            const int mm = kq * 4 + j;
            st[mm * NCM + col] = o[t][j] - sc - sxl[mm];
          }
        }
      }
    }
    // coalesced NT copy of 16x190 f32
    float* dst = out + nbase * NCM;
    const f32x4* src4 = (const f32x4*)st;
    for (int i = lane; i < TM * NCM / 4; i += 64) {
      f32x4 v = src4[i];
      __builtin_nontemporal_store(v, (f32x4*)dst + i);
    }
  }
}

extern "C" void kernel_launch(void* const* d_in, const int* in_sizes, int n_in,
                              void* d_out, int out_size, void* d_ws, size_t ws_size,
                              hipStream_t stream) {
  const float* x = (const float*)d_in[0];
  const float* x_var = (const float*)d_in[1];
  const float* protos = (const float*)d_in[2];
  const float* pvar = (const float*)d_in[3];
  const float* gam = (const float*)d_in[4];
  const float* bet = (const float*)d_in[5];
  const float* eps_x = (const float*)d_in[6];
  const float* eps_p = (const float*)d_in[7];
  float* out = (float*)d_out;

  ushort* Bp = (ushort*)d_ws;                          // 192*512*2 = 196608 B
  float* spc = (float*)((char*)d_ws + CMP * 512 * 2);  // 192*4 B

  proto_prep_kernel<<<CMP / 4, 256, 0, stream>>>(protos, pvar, gam, bet, eps_p, Bp, spc);
  fused_main_kernel<<<GRID_MAIN, 64, 0, stream>>>(x, x_var, gam, bet, eps_x, Bp, spc, out);
}